// Round 4
// baseline (90.262 us; speedup 1.0000x reference)
//
#include <hip/hip_runtime.h>

// Problem constants (match reference)
#define PB 8          // batches
#define PS 2048       // sequence length
#define PN 4096       // spans per batch
#define PD 256        // feature dim (f32) -> 64 f4 per row
#define CHUNK 16      // prefix chunk; MAX_W=16 <= CHUNK so a span straddles <=1 boundary
#define NCH (PS / CHUNK)   // 128 chunks per batch
// MAX_W = 16 -> width in [0,15]; start in [0, S-MAX_W) -> rows start..end in bounds.

typedef float f4 __attribute__((ext_vector_type(4)));
typedef int   i2 __attribute__((ext_vector_type(2)));

// ---------------------------------------------------------------------------
// Kernel A: chunk-local inclusive prefix along S (CHUNK=16) + per-chunk totals.
// grid = PB*NCH = 1024 blocks (b = blockIdx&7 -> XCD b owns batch b's P slice,
// 2.1 MiB, resident in that XCD's 4 MiB L2 for the span kernel's gathers).
// Block = 256 threads = 4 waves; wave w prefixes rows 4w..4w+3 in f4 registers,
// then an LDS carry pass adds the preceding waves' totals. Serial chain 4 (was
// 32 scalar). seq is streamed with non-temporal f4 loads (read once).
// ---------------------------------------------------------------------------
__global__ __launch_bounds__(256) void chunk_prefix_kernel(
    const float* __restrict__ seq,  // (B, S, D)
    float*       __restrict__ P,    // (B, S, D) chunk-local inclusive prefix
    float*       __restrict__ T)    // (B, NCH, D) chunk totals
{
    const int b    = blockIdx.x & 7;           // batch == XCD
    const int c    = blockIdx.x >> 3;          // chunk 0..NCH-1
    const int w    = threadIdx.x >> 6;         // wave 0..3 -> rows 4w..4w+3
    const int lane = threadIdx.x & 63;         // f4 column

    const size_t rowbase = ((size_t)b * PS + (size_t)c * CHUNK) * PD;
    const f4* sp = (const f4*)(seq + rowbase) + lane;
    f4*       pp = (f4*)(P + rowbase) + lane;

    const int r0 = w << 2;
    f4 v0 = __builtin_nontemporal_load(sp + (size_t)(r0 + 0) * 64);
    f4 v1 = __builtin_nontemporal_load(sp + (size_t)(r0 + 1) * 64);
    f4 v2 = __builtin_nontemporal_load(sp + (size_t)(r0 + 2) * 64);
    f4 v3 = __builtin_nontemporal_load(sp + (size_t)(r0 + 3) * 64);
    v1 += v0;
    v2 += v1;
    v3 += v2;                                  // local inclusive prefix of 4 rows

    __shared__ f4 tot[4][64];
    tot[w][lane] = v3;
    __syncthreads();

    f4 carry = (f4){0.f, 0.f, 0.f, 0.f};       // wave-uniform branches (scalar)
    if (w > 0) carry = tot[0][lane];
    if (w > 1) carry += tot[1][lane];
    if (w > 2) carry += tot[2][lane];

    v0 += carry;
    v1 += carry;
    v2 += carry;
    v3 += carry;

    pp[(size_t)(r0 + 0) * 64] = v0;            // normal stores: keep P in L2
    pp[(size_t)(r0 + 1) * 64] = v1;
    pp[(size_t)(r0 + 2) * 64] = v2;
    pp[(size_t)(r0 + 3) * 64] = v3;
    if (w == 3)
        ((f4*)(T + ((size_t)b * NCH + c) * PD))[lane] = v3;
}

// ---------------------------------------------------------------------------
// Kernel D: one wave per span; lane i owns f4 [4i,4i+4) of D=256.
// sum(rows start..end) = P[end] - m0*P[start-1] + (straddle ? T[chunk(start-1)] : 0)
//   m0 = (start>0); straddle = chunk(end) > chunk(start-1); start==0 => neither.
// 2 gather rows + ~0.5 avg L2-hot T row per span (vs 9.5 direct-gather rows).
// ---------------------------------------------------------------------------
__global__ __launch_bounds__(256) void span_mean_kernel(
    const float* __restrict__ P,       // (B, S, D)
    const float* __restrict__ T,       // (B, NCH, D)
    const int*   __restrict__ spans,   // (B, N, 2): start, end (inclusive)
    float*       __restrict__ out)     // (B, N, D)
{
    const int b       = blockIdx.x & 7;          // batch == XCD
    const int blk     = blockIdx.x >> 3;         // 0..1023 within batch
    const int span_ib = (blk << 2) | (threadIdx.x >> 6);   // 0..4095 in batch
    const int span    = (b << 12) | span_ib;     // global span id
    const int lane    = threadIdx.x & 63;

    // start/end for this span (wave-uniform -> scalarize). NT: don't pollute L2.
    const i2  se    = __builtin_nontemporal_load((const i2*)spans + span);
    const int start = __builtin_amdgcn_readfirstlane(se.x);
    const int end   = __builtin_amdgcn_readfirstlane(se.y);   // inclusive last row
    const int width = end - start;                            // 0..15

    const float inv = 1.0f / (float)(width + 1);
    const int   sm  = (start > 0) ? (start - 1) : 0;
    const float m0  = (start > 0) ? 1.0f : 0.0f;
    const int   cs  = sm >> 4;                   // CHUNK = 16
    const int   ce  = end >> 4;

    const f4* Pb = (const f4*)(P + (size_t)b * PS * PD) + lane;
    const f4 pe = Pb[(size_t)end * 64];
    const f4 ps = Pb[(size_t)sm * 64];

    f4 acc = pe - ps * m0;
    if (ce > cs) {                               // wave-uniform scalar branch
        const f4 tt = ((const f4*)(T + ((size_t)b * NCH + (size_t)cs) * PD))[lane];
        acc += tt;
    }
    acc *= inv;

    // Non-temporal store: keep the 33.5 MB output stream out of L2 so P stays.
    f4* outp = (f4*)(out + (size_t)span * PD) + lane;
    __builtin_nontemporal_store(acc, outp);
}

extern "C" void kernel_launch(void* const* d_in, const int* in_sizes, int n_in,
                              void* d_out, int out_size, void* d_ws, size_t ws_size,
                              hipStream_t stream) {
    const float* seq   = (const float*)d_in[0];   // (B,S,D) f32
    const int*   spans = (const int*)d_in[1];     // (B,N,2) i32
    float*       out   = (float*)d_out;           // (B,N,D) f32

    // Workspace layout: P (16.8 MB) then T (1 MB); ws is 256 MB.
    float* P = (float*)d_ws;
    float* T = P + (size_t)PB * PS * PD;

    chunk_prefix_kernel<<<dim3(PB * NCH), dim3(256), 0, stream>>>(seq, P, T);

    const int n_spans = PB * PN;                  // 32768
    span_mean_kernel<<<dim3(n_spans / 4), dim3(256), 0, stream>>>(P, T, spans, out);
}

// Round 5
// 85.164 us; speedup vs baseline: 1.0599x; 1.0599x over previous
//
#include <hip/hip_runtime.h>

// Problem constants (match reference)
#define PB 8          // batches
#define PS 2048       // sequence length
#define PN 4096       // spans per batch
#define PD 256        // feature dim (f32) -> 64 f4 per row
// MAX_W = 16 -> width in [0,15], count = width+1 in [1,16]
// setup guarantees start in [0, S-MAX_W) so rows start..start+15 are in bounds.

typedef float f4 __attribute__((ext_vector_type(4)));

// Sum exactly NR consecutive rows: all NR loads issued before the first use
// -> one memory round-trip per wave, minimal gather volume.
template<int NR>
__device__ __forceinline__ f4 sum_rows(const f4* __restrict__ b4) {
    f4 v[NR];
#pragma unroll
    for (int r = 0; r < NR; ++r) v[r] = b4[r * 64];   // row stride = PD/4 = 64 f4
    f4 acc = v[0];
#pragma unroll
    for (int r = 1; r < NR; ++r) acc += v[r];
    return acc;
}

// One wave (64 lanes) per span; lane i owns f4 [4i,4i+4) of D=256.
// Block = 256 threads = 4 spans. Grid = 8192 blocks.
//
// XCD-aware swizzle: batch = blockIdx % 8 keeps each XCD's gathers inside one
// batch's 2 MiB seq slice (fits the 4 MiB per-XCD L2).
//
// width is wave-uniform (readfirstlane) -> the switch is a scalar branch
// tree; each wave executes exactly width+1 loads in a single issue burst.
__global__ __launch_bounds__(256) void span_mean_kernel(
    const float* __restrict__ seq,     // (B, S, D) f32
    const int*   __restrict__ spans,   // (B, N, 2) i32: start, end
    float*       __restrict__ out)     // (B, N, D) f32
{
    const int b       = blockIdx.x & 7;          // batch == XCD (round-robin)
    const int blk     = blockIdx.x >> 3;         // 0..1023 within batch
    const int span_ib = (blk << 2) | (threadIdx.x >> 6);   // 0..4095 in batch
    const int span    = (b << 12) | span_ib;     // global span id
    const int lane    = threadIdx.x & 63;

    // start/width for this span (wave-uniform -> scalarize)
    const int2 se    = ((const int2*)spans)[span];
    const int  start = __builtin_amdgcn_readfirstlane(se.x);
    const int  width = __builtin_amdgcn_readfirstlane(se.y - se.x);  // 0..15

    const float inv = 1.0f / (float)(width + 1);

    const f4* b4 = (const f4*)(seq + (((size_t)b * PS + (size_t)start) * PD)) + lane;

    f4 acc;
    switch (width) {
        case 0:  acc = sum_rows<1>(b4);  break;
        case 1:  acc = sum_rows<2>(b4);  break;
        case 2:  acc = sum_rows<3>(b4);  break;
        case 3:  acc = sum_rows<4>(b4);  break;
        case 4:  acc = sum_rows<5>(b4);  break;
        case 5:  acc = sum_rows<6>(b4);  break;
        case 6:  acc = sum_rows<7>(b4);  break;
        case 7:  acc = sum_rows<8>(b4);  break;
        case 8:  acc = sum_rows<9>(b4);  break;
        case 9:  acc = sum_rows<10>(b4); break;
        case 10: acc = sum_rows<11>(b4); break;
        case 11: acc = sum_rows<12>(b4); break;
        case 12: acc = sum_rows<13>(b4); break;
        case 13: acc = sum_rows<14>(b4); break;
        case 14: acc = sum_rows<15>(b4); break;
        default: acc = sum_rows<16>(b4); break;
    }

    acc *= inv;

    // Plain store (NT store measured neutral-to-worse in R2).
    ((f4*)(out + (size_t)span * PD))[lane] = acc;
}

extern "C" void kernel_launch(void* const* d_in, const int* in_sizes, int n_in,
                              void* d_out, int out_size, void* d_ws, size_t ws_size,
                              hipStream_t stream) {
    const float* seq   = (const float*)d_in[0];   // (B,S,D) f32
    const int*   spans = (const int*)d_in[1];     // (B,N,2) i32
    float*       out   = (float*)d_out;           // (B,N,D) f32

    const int n_spans = PB * PN;                  // 32768
    dim3 grid(n_spans / 4);                       // 8192 blocks, 4 spans each
    dim3 block(256);
    span_mean_kernel<<<grid, block, 0, stream>>>(seq, spans, out);
}